// Round 1
// baseline (1009.784 us; speedup 1.0000x reference)
//
#include <hip/hip_runtime.h>

// ---------------------------------------------------------------------------
// SAG_atten_up: relu -> 3x block_norm+1x1conv+SiLU -> concat -> 3x3 conv(512->128)
//               -> 1x1 conv -> GELU -> 1x1 conv -> * residual
// Internal layout: NHWC fp16 activations, fp32 accumulation (MFMA 16x16x32 f16).
// block_norm(x1,s) folded into epilogue scalars (1x1 conv is per-pixel linear).
// ---------------------------------------------------------------------------

typedef _Float16 half8 __attribute__((ext_vector_type(8)));
typedef float    f32x4 __attribute__((ext_vector_type(4)));

// workspace byte offsets
#define OFF_BINS 0            // 16 f32 (relu block sums, 64x64 blocks)
#define OFF_INV  256          // 21 f32: [inv1, inv2[4], inv4[16]]
#define OFF_WF   512          // 5 * 16384 halfs (w1,w2,w3,wa,wb as [co][ci])
#define OFF_AMAT 164352       // 128*4608 halfs (wm as [co][tap*512+ci])
#define OFF_CAT  1344000      // 4*256*256*512 halfs (NHWC concat)
#define OFF_YMIX 269779456    // 4*256*256*128 halfs (NHWC mix output)
// total ws bytes needed = 336888320

__device__ __forceinline__ float silu_f(float y) { return y / (1.f + __expf(-y)); }

__device__ __forceinline__ void zero_acc(f32x4 acc[4][4]) {
#pragma unroll
  for (int mt = 0; mt < 4; ++mt)
#pragma unroll
    for (int nt = 0; nt < 4; ++nt)
#pragma unroll
      for (int r = 0; r < 4; ++r) acc[mt][nt][r] = 0.f;
}

// Wave-level 64x64 GEMM step over 32 k's.
// C[m][n] = sum_k sM_row(m)[k] * sN_row(n)[k]; rows hold WK octets (8 halfs each),
// octet o of row r stored at o ^ (r & (WK-1)) (bank swizzle).
// kko = octet offset of this 32-k chunk (0,4,8,12).
// c_frag[r] = C[m0+mt*16 + (lane>>4)*4 + r][n0+nt*16 + (lane&15)]
template <int WK>
__device__ __forceinline__ void gemm_step(const _Float16* __restrict__ sM,
                                          const _Float16* __restrict__ sN,
                                          int m0, int n0, int kko, int lane,
                                          f32x4 acc[4][4]) {
  const int r15 = lane & 15;
  const int quad = lane >> 4;
  half8 a[4], b[4];
#pragma unroll
  for (int mt = 0; mt < 4; ++mt) {
    int row = m0 + mt * 16 + r15;
    a[mt] = *(const half8*)&sM[row * (WK * 8) + (((kko + quad) ^ (row & (WK - 1))) * 8)];
  }
#pragma unroll
  for (int nt = 0; nt < 4; ++nt) {
    int row = n0 + nt * 16 + r15;
    b[nt] = *(const half8*)&sN[row * (WK * 8) + (((kko + quad) ^ (row & (WK - 1))) * 8)];
  }
#pragma unroll
  for (int mt = 0; mt < 4; ++mt)
#pragma unroll
    for (int nt = 0; nt < 4; ++nt)
      acc[mt][nt] =
          __builtin_amdgcn_mfma_f32_16x16x32_f16(a[mt], b[nt], acc[mt][nt], 0, 0, 0);
}

// ------------------------- prep: fp32 -> fp16 weights -----------------------
__global__ __launch_bounds__(256) void k_prep(const float* __restrict__ w1,
                                              const float* __restrict__ w2,
                                              const float* __restrict__ w3,
                                              const float* __restrict__ wa,
                                              const float* __restrict__ wb,
                                              const float* __restrict__ wm,
                                              _Float16* __restrict__ wf16,
                                              _Float16* __restrict__ amat) {
  const float* wsrc[5] = {w1, w2, w3, wa, wb};
  const int total = 5 * 16384 + 128 * 4608;
  for (int idx = blockIdx.x * 256 + threadIdx.x; idx < total; idx += gridDim.x * 256) {
    if (idx < 81920) {
      int which = idx >> 14, o = idx & 16383;
      wf16[idx] = (_Float16)wsrc[which][o];
    } else {
      int t = idx - 81920;
      int co = t / 4608, k = t - co * 4608;
      int tap = k >> 9, ci = k & 511;
      amat[t] = (_Float16)wm[(co * 512 + ci) * 9 + tap];  // wm: [co][ci][3][3]
    }
  }
}

// ------------- transpose x NCHW f32 -> cat[...,0:128] NHWC f16 + block sums -
__global__ __launch_bounds__(256) void k_transpose(const float* __restrict__ x,
                                                   _Float16* __restrict__ cat,
                                                   float* __restrict__ bins) {
  __shared__ float tile[64 * 132];  // [px][ci], pad 4 -> conflict-free both phases
  __shared__ float sred[256];
  const int tid = threadIdx.x;
  const int gid = blockIdx.x;            // 4096 blocks
  const int jt = gid & 3, i = (gid >> 2) & 255, b = gid >> 10;
  const int j0 = jt * 64;
  float s = 0.f;
  for (int it = 0; it < 32; ++it) {
    int lid = tid + it * 256;
    int ci = lid >> 6, px = lid & 63;
    float v = x[(b * 128 + ci) * 65536 + i * 256 + j0 + px];
    s += fmaxf(v, 0.f);
    tile[px * 132 + ci] = v;
  }
  __syncthreads();
  for (int it = 0; it < 4; ++it) {
    int lid = tid + it * 256;
    int px = lid >> 4, part = lid & 15;
    half8 h;
#pragma unroll
    for (int j = 0; j < 8; ++j) h[j] = (_Float16)tile[px * 132 + part * 8 + j];
    *(half8*)&cat[(size_t)((b * 256 + i) * 256 + j0 + px) * 512 + part * 8] = h;
  }
  sred[tid] = s;
  __syncthreads();
  for (int off = 128; off > 0; off >>= 1) {
    if (tid < off) sred[tid] += sred[tid + off];
    __syncthreads();
  }
  if (tid == 0) atomicAdd(&bins[(i >> 6) * 4 + jt], sred[0]);
}

// ----------------------------- inverse means --------------------------------
__global__ void k_invm(const float* __restrict__ bins, float* __restrict__ inv) {
  if (threadIdx.x == 0 && blockIdx.x == 0) {
    float s4[16], tot = 0.f;
    for (int k = 0; k < 16; ++k) s4[k] = bins[k];
    for (int k = 0; k < 16; ++k) inv[5 + k] = 1.f / (s4[k] * (1.f / 2097152.f) + 1e-4f);
    for (int p = 0; p < 2; ++p)
      for (int q = 0; q < 2; ++q) {
        float s2 = s4[(2 * p) * 4 + 2 * q] + s4[(2 * p) * 4 + 2 * q + 1] +
                   s4[(2 * p + 1) * 4 + 2 * q] + s4[(2 * p + 1) * 4 + 2 * q + 1];
        tot += s2;
        inv[1 + p * 2 + q] = 1.f / (s2 * (1.f / 8388608.f) + 1e-4f);
      }
    inv[0] = 1.f / (tot * (1.f / 33554432.f) + 1e-4f);
  }
}

// ------- k1: shared relu(x) tile -> 3 scale 1x1 convs -> SiLU -> cat[1..3] --
__global__ __launch_bounds__(256) void k1_sconv(_Float16* __restrict__ cat,
                                                const _Float16* __restrict__ wf16,
                                                const float* __restrict__ g1,
                                                const float* __restrict__ b1,
                                                const float* __restrict__ g2,
                                                const float* __restrict__ b2,
                                                const float* __restrict__ g3,
                                                const float* __restrict__ b3,
                                                const float* __restrict__ inv) {
  __shared__ _Float16 sAct[128 * 128];  // [px][ci] swizzled, WK=16
  __shared__ _Float16 sW[128 * 128];    // [co][ci] swizzled
  const int tid = threadIdx.x, lane = tid & 63, wave = tid >> 6;
  const int m0 = (wave >> 1) * 64, n0 = (wave & 1) * 64;
  const int gid = blockIdx.x;  // 2048
  const int jh = gid & 1, i = (gid >> 1) & 255, b = gid >> 9;
  const size_t rowbase = (size_t)((b * 256 + i) * 256 + jh * 128);

  for (int it = 0; it < 8; ++it) {
    int lid = tid + it * 256;
    int px = lid >> 4, part = lid & 15;
    half8 v = *(const half8*)&cat[(rowbase + px) * 512 + part * 8];
#pragma unroll
    for (int j = 0; j < 8; ++j) v[j] = (v[j] > (_Float16)0.f) ? v[j] : (_Float16)0.f;
    *(half8*)&sAct[px * 128 + ((part ^ (px & 15)) * 8)] = v;
  }

  const float* gs[3] = {g1, g2, g3};
  const float* bs[3] = {b1, b2, b3};
  for (int s = 0; s < 3; ++s) {
    __syncthreads();  // prior GEMM reads of sW done; also orders sAct writes (s==0)
    for (int it = 0; it < 8; ++it) {
      int lid = tid + it * 256;
      int co = lid >> 4, part = lid & 15;
      *(half8*)&sW[co * 128 + ((part ^ (co & 15)) * 8)] =
          *(const half8*)&wf16[s * 16384 + co * 128 + part * 8];
    }
    __syncthreads();
    f32x4 acc[4][4];
    zero_acc(acc);
#pragma unroll
    for (int ks = 0; ks < 4; ++ks) gemm_step<16>(sAct, sW, m0, n0, ks * 4, lane, acc);

    // block_norm scalars: conv(x1*alpha) = alpha*conv(x1)
    float a_lo, a_hi;
    if (s == 0) {
      a_lo = a_hi = inv[0];
    } else if (s == 1) {
      a_lo = a_hi = inv[1 + (i >> 7) * 2 + jh];
    } else {
      int base = 5 + (i >> 6) * 4 + jh * 2;
      a_lo = inv[base];
      a_hi = inv[base + 1];
    }
#pragma unroll
    for (int nt = 0; nt < 4; ++nt) {
      int co = n0 + nt * 16 + (lane & 15);
      float gg = gs[s][co], sh = bs[s][co];
#pragma unroll
      for (int mt = 0; mt < 4; ++mt) {
#pragma unroll
        for (int r = 0; r < 4; ++r) {
          int px = m0 + mt * 16 + (lane >> 4) * 4 + r;
          float al = (px < 64) ? a_lo : a_hi;
          float y = acc[mt][nt][r] * al * gg + sh;
          cat[(rowbase + px) * 512 + (s + 1) * 128 + co] = (_Float16)silu_f(y);
        }
      }
    }
  }
}

// ---------------- k2: 3x3 mix conv (512->128) implicit GEMM ----------------
__global__ __launch_bounds__(256) void k2_mix(const _Float16* __restrict__ cat,
                                              const _Float16* __restrict__ amat,
                                              const float* __restrict__ gm,
                                              const float* __restrict__ bm,
                                              _Float16* __restrict__ ymix) {
  __shared__ _Float16 sAct[128 * 64];  // [px][64k] swizzled, WK=8
  __shared__ _Float16 sW[128 * 64];    // [co][64k] swizzled
  const int tid = threadIdx.x, lane = tid & 63, wave = tid >> 6;
  const int m0 = (wave >> 1) * 64, n0 = (wave & 1) * 64;
  const int gid = blockIdx.x;  // 2048
  const int jh = gid & 1, i = (gid >> 1) & 255, b = gid >> 9;

  f32x4 acc[4][4];
  zero_acc(acc);

  for (int tap = 0; tap < 9; ++tap) {
    const int di = tap / 3, dj = tap % 3;
    const int ii = i + di - 1;
    if (ii < 0 || ii >= 256) continue;  // block-uniform
    const _Float16* srcRow = cat + (size_t)((b * 256 + ii) * 256) * 512;
    for (int c64 = 0; c64 < 8; ++c64) {
      const int kbase = tap * 512 + c64 * 64;
      __syncthreads();  // previous chunk's LDS reads done
#pragma unroll
      for (int it = 0; it < 4; ++it) {
        int lid = tid + it * 256;
        int row = lid >> 3, part = lid & 7;
        // weights
        *(half8*)&sW[row * 64 + ((part ^ (row & 7)) * 8)] =
            *(const half8*)&amat[row * 4608 + kbase + part * 8];
        // activations (halo along j)
        int jj = jh * 128 + row + dj - 1;
        half8 v;
#pragma unroll
        for (int j = 0; j < 8; ++j) v[j] = (_Float16)0.f;
        if (jj >= 0 && jj < 256)
          v = *(const half8*)&srcRow[(size_t)jj * 512 + c64 * 64 + part * 8];
        *(half8*)&sAct[row * 64 + ((part ^ (row & 7)) * 8)] = v;
      }
      __syncthreads();
      gemm_step<8>(sAct, sW, m0, n0, 0, lane, acc);
      gemm_step<8>(sAct, sW, m0, n0, 4, lane, acc);
    }
  }

  const int outbase = (b * 256 + i) * 256 + jh * 128;
#pragma unroll
  for (int nt = 0; nt < 4; ++nt) {
    int co = n0 + nt * 16 + (lane & 15);
    float gg = gm[co], sh = bm[co];
#pragma unroll
    for (int mt = 0; mt < 4; ++mt) {
#pragma unroll
      for (int r = 0; r < 4; ++r) {
        int px = m0 + mt * 16 + (lane >> 4) * 4 + r;
        float y = acc[mt][nt][r] * gg + sh;
        ymix[(size_t)(outbase + px) * 128 + co] = (_Float16)silu_f(y);
      }
    }
  }
}

// ------ k3: 1x1 conv + SiLU -> GELU -> 1x1 conv + SiLU -> * residual -------
__global__ __launch_bounds__(256) void k3_tail(const _Float16* __restrict__ ymix,
                                               const _Float16* __restrict__ wfa,
                                               const _Float16* __restrict__ wfb,
                                               const float* __restrict__ ga,
                                               const float* __restrict__ ba,
                                               const float* __restrict__ gb,
                                               const float* __restrict__ bbv,
                                               const float* __restrict__ x,
                                               float* __restrict__ out) {
  __shared__ _Float16 sAct[128 * 128];  // ymix tile, then mid (gelu) tile
  __shared__ _Float16 sW[128 * 128];    // wa, then wb
  const int tid = threadIdx.x, lane = tid & 63, wave = tid >> 6;
  const int m0 = (wave >> 1) * 64, n0 = (wave & 1) * 64;
  const int gid = blockIdx.x;  // 2048
  const int jh = gid & 1, i = (gid >> 1) & 255, b = gid >> 9;
  const size_t rowbase = (size_t)((b * 256 + i) * 256 + jh * 128);

  for (int it = 0; it < 8; ++it) {
    int lid = tid + it * 256;
    int row = lid >> 4, part = lid & 15;
    *(half8*)&sAct[row * 128 + ((part ^ (row & 15)) * 8)] =
        *(const half8*)&ymix[(rowbase + row) * 128 + part * 8];
    *(half8*)&sW[row * 128 + ((part ^ (row & 15)) * 8)] =
        *(const half8*)&wfa[row * 128 + part * 8];
  }
  __syncthreads();
  // GEMM1: C[co][px] = sum_ci wa[co][ci] * ymix[px][ci]
  f32x4 acc[4][4];
  zero_acc(acc);
#pragma unroll
  for (int ks = 0; ks < 4; ++ks) gemm_step<16>(sW, sAct, m0, n0, ks * 4, lane, acc);
  __syncthreads();  // GEMM1 LDS reads done before overwriting

  // epilogue1: mid = gelu(silu(t*ga+ba)) -> sAct (as [px][ci]); stage wb -> sW
#pragma unroll
  for (int mt = 0; mt < 4; ++mt) {
#pragma unroll
    for (int r = 0; r < 4; ++r) {
      int co = m0 + mt * 16 + (lane >> 4) * 4 + r;
      float gg = ga[co], sh = ba[co];
#pragma unroll
      for (int nt = 0; nt < 4; ++nt) {
        int px = n0 + nt * 16 + (lane & 15);
        float y = acc[mt][nt][r] * gg + sh;
        float sv = silu_f(y);
        float gl = 0.5f * sv * (1.f + erff(sv * 0.70710678118f));
        sAct[px * 128 + (((co >> 3) ^ (px & 15)) * 8) + (co & 7)] = (_Float16)gl;
      }
    }
  }
  for (int it = 0; it < 8; ++it) {
    int lid = tid + it * 256;
    int co = lid >> 4, part = lid & 15;
    *(half8*)&sW[co * 128 + ((part ^ (co & 15)) * 8)] =
        *(const half8*)&wfb[co * 128 + part * 8];
  }
  __syncthreads();
  // GEMM2: C[co][px] = sum_ci wb[co][ci] * mid[px][ci]
  f32x4 acc2[4][4];
  zero_acc(acc2);
#pragma unroll
  for (int ks = 0; ks < 4; ++ks) gemm_step<16>(sW, sAct, m0, n0, ks * 4, lane, acc2);

#pragma unroll
  for (int mt = 0; mt < 4; ++mt) {
#pragma unroll
    for (int r = 0; r < 4; ++r) {
      int co = m0 + mt * 16 + (lane >> 4) * 4 + r;
      float gg = gb[co], sh = bbv[co];
      size_t base = (size_t)(b * 128 + co) * 65536 + i * 256 + jh * 128;
#pragma unroll
      for (int nt = 0; nt < 4; ++nt) {
        int px = n0 + nt * 16 + (lane & 15);
        float y = acc2[mt][nt][r] * gg + sh;
        out[base + px] = silu_f(y) * x[base + px];  // * residual, NCHW fp32
      }
    }
  }
}

// ---------------------------------------------------------------------------
extern "C" void kernel_launch(void* const* d_in, const int* in_sizes, int n_in,
                              void* d_out, int out_size, void* d_ws, size_t ws_size,
                              hipStream_t stream) {
  (void)in_sizes; (void)n_in; (void)out_size; (void)ws_size;
  const float* x  = (const float*)d_in[0];
  const float* w1 = (const float*)d_in[1];
  const float* g1 = (const float*)d_in[2];
  const float* b1 = (const float*)d_in[3];
  const float* w2 = (const float*)d_in[4];
  const float* g2 = (const float*)d_in[5];
  const float* b2 = (const float*)d_in[6];
  const float* w3 = (const float*)d_in[7];
  const float* g3 = (const float*)d_in[8];
  const float* b3 = (const float*)d_in[9];
  const float* wm = (const float*)d_in[10];
  const float* gm = (const float*)d_in[11];
  const float* bm = (const float*)d_in[12];
  const float* wa = (const float*)d_in[13];
  const float* ga = (const float*)d_in[14];
  const float* ba = (const float*)d_in[15];
  const float* wb = (const float*)d_in[16];
  const float* gb = (const float*)d_in[17];
  const float* bb = (const float*)d_in[18];

  char* ws = (char*)d_ws;
  float*    bins = (float*)(ws + OFF_BINS);
  float*    inv  = (float*)(ws + OFF_INV);
  _Float16* wf16 = (_Float16*)(ws + OFF_WF);
  _Float16* amat = (_Float16*)(ws + OFF_AMAT);
  _Float16* cat  = (_Float16*)(ws + OFF_CAT);
  _Float16* ymix = (_Float16*)(ws + OFF_YMIX);
  float*    out  = (float*)d_out;

  hipMemsetAsync(bins, 0, 64, stream);
  k_prep<<<512, 256, 0, stream>>>(w1, w2, w3, wa, wb, wm, wf16, amat);
  k_transpose<<<4096, 256, 0, stream>>>(x, cat, bins);
  k_invm<<<1, 64, 0, stream>>>(bins, inv);
  k1_sconv<<<2048, 256, 0, stream>>>(cat, wf16, g1, b1, g2, b2, g3, b3, inv);
  k2_mix<<<2048, 256, 0, stream>>>(cat, amat, gm, bm, ymix);
  k3_tail<<<2048, 256, 0, stream>>>(ymix, wf16 + 3 * 16384, wf16 + 4 * 16384,
                                    ga, ba, gb, bb, x, out);
}

// Round 2
// 886.476 us; speedup vs baseline: 1.1391x; 1.1391x over previous
//
#include <hip/hip_runtime.h>

// ---------------------------------------------------------------------------
// SAG_atten_up: relu -> 3x block_norm+1x1conv+SiLU -> concat -> 3x3 conv(512->128)
//               -> 1x1 conv -> GELU -> 1x1 conv -> * residual
// Internal layout: NHWC fp16 activations, fp32 accumulation (MFMA 16x16x32 f16).
// block_norm(x1,s) folded into epilogue scalars (1x1 conv is per-pixel linear).
// R2: k2 restructured — dj-reuse (stage one 130-px act strip per (ii,c64), run
//     3 shifted GEMMs), weights as fragment-major direct-from-L2 loads (no LDS),
//     global_load_lds(16B) staging with cross-stage prefetch double-buffer.
//     k1/k2 epilogues: LDS round-trip -> b128 vector global stores.
// ---------------------------------------------------------------------------

typedef _Float16 half8 __attribute__((ext_vector_type(8)));
typedef float    f32x4 __attribute__((ext_vector_type(4)));

// workspace byte offsets
#define OFF_BINS 0            // 16 f32 (relu block sums, 64x64 blocks)
#define OFF_INV  256          // 21 f32: [inv1, inv2[4], inv4[16]]
#define OFF_WF   512          // 5 * 16384 halfs (w1,w2,w3,wa,wb as [co][ci])
#define OFF_AMAT 164352       // 589824 halfs (wm fragment-major, see k_prep)
#define OFF_CAT  1344000      // 4*256*256*512 halfs (NHWC concat)
#define OFF_YMIX 269779456    // 4*256*256*128 halfs (NHWC mix output)
// total ws bytes needed = 336888320

__device__ __forceinline__ float silu_f(float y) { return y / (1.f + __expf(-y)); }

__device__ __forceinline__ void zero_acc(f32x4 acc[4][4]) {
#pragma unroll
  for (int mt = 0; mt < 4; ++mt)
#pragma unroll
    for (int nt = 0; nt < 4; ++nt)
#pragma unroll
      for (int r = 0; r < 4; ++r) acc[mt][nt][r] = 0.f;
}

// Wave-level 64x64 GEMM step over 32 k's (both operands LDS, XOR-octet swizzle).
// c_frag[r] = C[m0+mt*16 + (lane>>4)*4 + r][n0+nt*16 + (lane&15)]
template <int WK>
__device__ __forceinline__ void gemm_step(const _Float16* __restrict__ sM,
                                          const _Float16* __restrict__ sN,
                                          int m0, int n0, int kko, int lane,
                                          f32x4 acc[4][4]) {
  const int r15 = lane & 15;
  const int quad = lane >> 4;
  half8 a[4], b[4];
#pragma unroll
  for (int mt = 0; mt < 4; ++mt) {
    int row = m0 + mt * 16 + r15;
    a[mt] = *(const half8*)&sM[row * (WK * 8) + (((kko + quad) ^ (row & (WK - 1))) * 8)];
  }
#pragma unroll
  for (int nt = 0; nt < 4; ++nt) {
    int row = n0 + nt * 16 + r15;
    b[nt] = *(const half8*)&sN[row * (WK * 8) + (((kko + quad) ^ (row & (WK - 1))) * 8)];
  }
#pragma unroll
  for (int mt = 0; mt < 4; ++mt)
#pragma unroll
    for (int nt = 0; nt < 4; ++nt)
      acc[mt][nt] =
          __builtin_amdgcn_mfma_f32_16x16x32_f16(a[mt], b[nt], acc[mt][nt], 0, 0, 0);
}

// ------------------------- prep: fp32 -> fp16 weights -----------------------
// amat fragment-major: idx = (((tap*16 + kc)*8 + cg)*64 + lane)*8 + e
//   holds wm[co = cg*16 + (lane&15)][kl = kc*32 + (lane>>4)*8 + e] at tap,
//   i.e. one wave's B-fragment (16 co x 32 k) is a contiguous 1 KB block.
__global__ __launch_bounds__(256) void k_prep(const float* __restrict__ w1,
                                              const float* __restrict__ w2,
                                              const float* __restrict__ w3,
                                              const float* __restrict__ wa,
                                              const float* __restrict__ wb,
                                              const float* __restrict__ wm,
                                              _Float16* __restrict__ wf16,
                                              _Float16* __restrict__ amat) {
  const float* wsrc[5] = {w1, w2, w3, wa, wb};
  const int total = 81920 + 589824;
  for (int idx = blockIdx.x * 256 + threadIdx.x; idx < total; idx += gridDim.x * 256) {
    if (idx < 81920) {
      int which = idx >> 14, o = idx & 16383;
      wf16[idx] = (_Float16)wsrc[which][o];
    } else {
      int t = idx - 81920;
      int e = t & 7, ln = (t >> 3) & 63, cg = (t >> 9) & 7;
      int kc = (t >> 12) & 15, tap = t >> 16;
      int co = cg * 16 + (ln & 15);
      int kl = kc * 32 + (ln >> 4) * 8 + e;
      amat[t] = (_Float16)wm[(co * 512 + kl) * 9 + tap];  // wm: [co][ci][3][3]
    }
  }
}

// ------------- transpose x NCHW f32 -> cat[...,0:128] NHWC f16 + block sums -
__global__ __launch_bounds__(256) void k_transpose(const float* __restrict__ x,
                                                   _Float16* __restrict__ cat,
                                                   float* __restrict__ bins) {
  __shared__ float tile[64 * 132];  // [px][ci], pad 4 -> conflict-free both phases
  __shared__ float sred[256];
  const int tid = threadIdx.x;
  const int gid = blockIdx.x;            // 4096 blocks
  const int jt = gid & 3, i = (gid >> 2) & 255, b = gid >> 10;
  const int j0 = jt * 64;
  float s = 0.f;
  for (int it = 0; it < 32; ++it) {
    int lid = tid + it * 256;
    int ci = lid >> 6, px = lid & 63;
    float v = x[(b * 128 + ci) * 65536 + i * 256 + j0 + px];
    s += fmaxf(v, 0.f);
    tile[px * 132 + ci] = v;
  }
  __syncthreads();
  for (int it = 0; it < 4; ++it) {
    int lid = tid + it * 256;
    int px = lid >> 4, part = lid & 15;
    half8 h;
#pragma unroll
    for (int j = 0; j < 8; ++j) h[j] = (_Float16)tile[px * 132 + part * 8 + j];
    *(half8*)&cat[(size_t)((b * 256 + i) * 256 + j0 + px) * 512 + part * 8] = h;
  }
  sred[tid] = s;
  __syncthreads();
  for (int off = 128; off > 0; off >>= 1) {
    if (tid < off) sred[tid] += sred[tid + off];
    __syncthreads();
  }
  if (tid == 0) atomicAdd(&bins[(i >> 6) * 4 + jt], sred[0]);
}

// ----------------------------- inverse means --------------------------------
__global__ void k_invm(const float* __restrict__ bins, float* __restrict__ inv) {
  if (threadIdx.x == 0 && blockIdx.x == 0) {
    float s4[16], tot = 0.f;
    for (int k = 0; k < 16; ++k) s4[k] = bins[k];
    for (int k = 0; k < 16; ++k) inv[5 + k] = 1.f / (s4[k] * (1.f / 2097152.f) + 1e-4f);
    for (int p = 0; p < 2; ++p)
      for (int q = 0; q < 2; ++q) {
        float s2 = s4[(2 * p) * 4 + 2 * q] + s4[(2 * p) * 4 + 2 * q + 1] +
                   s4[(2 * p + 1) * 4 + 2 * q] + s4[(2 * p + 1) * 4 + 2 * q + 1];
        tot += s2;
        inv[1 + p * 2 + q] = 1.f / (s2 * (1.f / 8388608.f) + 1e-4f);
      }
    inv[0] = 1.f / (tot * (1.f / 33554432.f) + 1e-4f);
  }
}

// ------- k1: shared relu(x) tile -> 3 scale 1x1 convs -> SiLU -> cat[1..3] --
__global__ __launch_bounds__(256) void k1_sconv(_Float16* __restrict__ cat,
                                                const _Float16* __restrict__ wf16,
                                                const float* __restrict__ g1,
                                                const float* __restrict__ b1,
                                                const float* __restrict__ g2,
                                                const float* __restrict__ b2,
                                                const float* __restrict__ g3,
                                                const float* __restrict__ b3,
                                                const float* __restrict__ inv) {
  __shared__ _Float16 sAct[128 * 128];  // [px][ci] swizzled, WK=16
  __shared__ _Float16 sW[128 * 128];    // [co][ci] swizzled; reused as epi scratch
  const int tid = threadIdx.x, lane = tid & 63, wave = tid >> 6;
  const int m0 = (wave >> 1) * 64, n0 = (wave & 1) * 64;
  const int gid = blockIdx.x;  // 2048
  const int jh = gid & 1, i = (gid >> 1) & 255, b = gid >> 9;
  const size_t rowbase = (size_t)((b * 256 + i) * 256 + jh * 128);

  for (int it = 0; it < 8; ++it) {
    int lid = tid + it * 256;
    int px = lid >> 4, part = lid & 15;
    half8 v = *(const half8*)&cat[(rowbase + px) * 512 + part * 8];
#pragma unroll
    for (int j = 0; j < 8; ++j) v[j] = (v[j] > (_Float16)0.f) ? v[j] : (_Float16)0.f;
    *(half8*)&sAct[px * 128 + ((part ^ (px & 15)) * 8)] = v;
  }

  const float* gs[3] = {g1, g2, g3};
  const float* bs[3] = {b1, b2, b3};
  for (int s = 0; s < 3; ++s) {
    __syncthreads();  // prior epilogue reads of sW done; orders sAct writes (s==0)
    for (int it = 0; it < 8; ++it) {
      int lid = tid + it * 256;
      int co = lid >> 4, part = lid & 15;
      *(half8*)&sW[co * 128 + ((part ^ (co & 15)) * 8)] =
          *(const half8*)&wf16[s * 16384 + co * 128 + part * 8];
    }
    __syncthreads();
    f32x4 acc[4][4];
    zero_acc(acc);
#pragma unroll
    for (int ks = 0; ks < 4; ++ks) gemm_step<16>(sAct, sW, m0, n0, ks * 4, lane, acc);

    // block_norm scalars: conv(x1*alpha) = alpha*conv(x1)
    float a_lo, a_hi;
    if (s == 0) {
      a_lo = a_hi = inv[0];
    } else if (s == 1) {
      a_lo = a_hi = inv[1 + (i >> 7) * 2 + jh];
    } else {
      int base = 5 + (i >> 6) * 4 + jh * 2;
      a_lo = inv[base];
      a_hi = inv[base + 1];
    }
    __syncthreads();  // GEMM reads of sW done -> reuse as scratch
#pragma unroll
    for (int nt = 0; nt < 4; ++nt) {
      int co = n0 + nt * 16 + (lane & 15);
      float gg = gs[s][co], sh = bs[s][co];
#pragma unroll
      for (int mt = 0; mt < 4; ++mt) {
#pragma unroll
        for (int r = 0; r < 4; ++r) {
          int px = m0 + mt * 16 + (lane >> 4) * 4 + r;
          float al = (px < 64) ? a_lo : a_hi;
          float y = acc[mt][nt][r] * al * gg + sh;
          sW[px * 128 + (((co >> 3) ^ (px & 15)) * 8) + (co & 7)] = (_Float16)silu_f(y);
        }
      }
    }
    __syncthreads();
    for (int it = 0; it < 8; ++it) {
      int lid = tid + it * 256;
      int px = lid >> 4, o = lid & 15;
      half8 v = *(half8*)&sW[px * 128 + ((o ^ (px & 15)) * 8)];
      *(half8*)&cat[(rowbase + px) * 512 + (s + 1) * 128 + o * 8] = v;
    }
  }
}

// ---------------- k2: 3x3 mix conv (512->128) implicit GEMM ----------------
// Stage = one (ii, c64): 130-px act strip (64 ch) via global_load_lds into a
// double buffer; 3 dj taps x 2 k-chunks of GEMM per stage; weights read as
// coalesced fragments straight from L2 (fragment-major amat).
__device__ __forceinline__ void k2_stage(const _Float16* __restrict__ cat,
                                         _Float16* __restrict__ buf,
                                         int b, int ii, int jh, int c64,
                                         int lane, int wave) {
  const _Float16* src = cat + (size_t)((b * 256 + ii) * 256) * 512 + c64 * 64;
  const int rsub = lane >> 3, l7 = lane & 7;
#pragma unroll
  for (int it = 0; it < 4; ++it) {
    int rb = (wave * 4 + it) * 8;
    int row = rb + rsub;
    int j = jh * 128 + row - 1;
    int part = l7 ^ (row & 7);  // source permute compensates lane-ordered LDS dest
    if ((unsigned)j < 256u)
      __builtin_amdgcn_global_load_lds(
          (const __attribute__((address_space(1))) void*)(src + (size_t)j * 512 + part * 8),
          (__attribute__((address_space(3))) void*)(buf + rb * 64), 16, 0, 0);
  }
  if (wave == 3) {  // rows 128,129 (16 lanes)
    int row = 128 + rsub;
    int j = jh * 128 + row - 1;
    int part = l7 ^ (row & 7);
    if (lane < 16 && (unsigned)j < 256u)
      __builtin_amdgcn_global_load_lds(
          (const __attribute__((address_space(1))) void*)(src + (size_t)j * 512 + part * 8),
          (__attribute__((address_space(3))) void*)(buf + 128 * 64), 16, 0, 0);
  }
}

__global__ __launch_bounds__(256) void k2_mix(const _Float16* __restrict__ cat,
                                              const _Float16* __restrict__ amat,
                                              const float* __restrict__ gm,
                                              const float* __restrict__ bm,
                                              _Float16* __restrict__ ymix) {
  __shared__ _Float16 sAct[2][132 * 64];  // double-buffered act strip
  const int tid = threadIdx.x, lane = tid & 63, wave = tid >> 6;
  const int m0 = (wave >> 1) * 64, n0 = (wave & 1) * 64;
  const int gid = blockIdx.x;  // 2048
  const int jh = gid & 1, i = (gid >> 1) & 255, b = gid >> 9;

  // the one always-invalid j row (j=-1 for jh=0, j=256 for jh=1): zero in both bufs
  if (tid < 16) {
    int ez = (jh == 0) ? 0 : 129;
    half8 z = {};
    *(half8*)&sAct[tid >> 3][ez * 64 + (tid & 7) * 8] = z;
  }

  int dits[3], nd = 0;
#pragma unroll
  for (int dit = 0; dit < 3; ++dit) {
    int ii = i - 1 + dit;
    if (ii >= 0 && ii < 256) dits[nd++] = dit;
  }
  const int nst = nd * 8;  // stage s: dit = dits[s>>3], c64 = s&7

  k2_stage(cat, sAct[0], b, i - 1 + dits[0], jh, 0, lane, wave);

  f32x4 acc[4][4];
  zero_acc(acc);
  const int r15 = lane & 15, quad = lane >> 4;
  const int cg0 = n0 >> 4;

  for (int s = 0; s < nst; ++s) {
    __syncthreads();  // drains DMA(s) (compiler vmcnt(0)); frees buf[(s+1)&1]
    if (s + 1 < nst)  // prefetch next stage during this stage's compute
      k2_stage(cat, sAct[(s + 1) & 1], b, i - 1 + dits[(s + 1) >> 3], jh,
               (s + 1) & 7, lane, wave);
    const int dit = dits[s >> 3], c64 = s & 7;
    const _Float16* buf = sAct[s & 1];
#pragma unroll
    for (int dj = 0; dj < 3; ++dj) {
      const int tap = dit * 3 + dj;
#pragma unroll
      for (int kcl = 0; kcl < 2; ++kcl) {
        const _Float16* bb =
            amat + ((((size_t)(tap * 16 + c64 * 2 + kcl)) * 8 + cg0) * 64 + lane) * 8;
        half8 a[4], bf[4];
#pragma unroll
        for (int nt = 0; nt < 4; ++nt) bf[nt] = *(const half8*)&bb[nt * 512];
#pragma unroll
        for (int mt = 0; mt < 4; ++mt) {
          int row = m0 + mt * 16 + r15 + dj;
          a[mt] = *(const half8*)&buf[row * 64 + (((kcl * 4 + quad) ^ (row & 7)) * 8)];
        }
#pragma unroll
        for (int mt = 0; mt < 4; ++mt)
#pragma unroll
          for (int nt = 0; nt < 4; ++nt)
            acc[mt][nt] = __builtin_amdgcn_mfma_f32_16x16x32_f16(a[mt], bf[nt],
                                                                 acc[mt][nt], 0, 0, 0);
      }
    }
  }

  // epilogue: scalars+SiLU -> LDS scratch (f16, swizzled) -> b128 stores
  __syncthreads();
  _Float16* scratch = &sAct[0][0];  // 16384 halfs needed, 16896 available
  const int outbase = (b * 256 + i) * 256 + jh * 128;
#pragma unroll
  for (int nt = 0; nt < 4; ++nt) {
    int co = n0 + nt * 16 + r15;
    float gg = gm[co], sh = bm[co];
#pragma unroll
    for (int mt = 0; mt < 4; ++mt)
#pragma unroll
      for (int r = 0; r < 4; ++r) {
        int px = m0 + mt * 16 + quad * 4 + r;
        float y = acc[mt][nt][r] * gg + sh;
        scratch[px * 128 + (((co >> 3) ^ (px & 15)) * 8) + (co & 7)] =
            (_Float16)silu_f(y);
      }
  }
  __syncthreads();
  for (int it = 0; it < 8; ++it) {
    int lid = tid + it * 256;
    int px = lid >> 4, o = lid & 15;
    half8 v = *(half8*)&scratch[px * 128 + ((o ^ (px & 15)) * 8)];
    *(half8*)&ymix[(size_t)(outbase + px) * 128 + o * 8] = v;
  }
}

// ------ k3: 1x1 conv + SiLU -> GELU -> 1x1 conv + SiLU -> * residual -------
__global__ __launch_bounds__(256) void k3_tail(const _Float16* __restrict__ ymix,
                                               const _Float16* __restrict__ wfa,
                                               const _Float16* __restrict__ wfb,
                                               const float* __restrict__ ga,
                                               const float* __restrict__ ba,
                                               const float* __restrict__ gb,
                                               const float* __restrict__ bbv,
                                               const float* __restrict__ x,
                                               float* __restrict__ out) {
  __shared__ _Float16 sAct[128 * 128];  // ymix tile, then mid (gelu) tile
  __shared__ _Float16 sW[128 * 128];    // wa, then wb
  const int tid = threadIdx.x, lane = tid & 63, wave = tid >> 6;
  const int m0 = (wave >> 1) * 64, n0 = (wave & 1) * 64;
  const int gid = blockIdx.x;  // 2048
  const int jh = gid & 1, i = (gid >> 1) & 255, b = gid >> 9;
  const size_t rowbase = (size_t)((b * 256 + i) * 256 + jh * 128);

  for (int it = 0; it < 8; ++it) {
    int lid = tid + it * 256;
    int row = lid >> 4, part = lid & 15;
    *(half8*)&sAct[row * 128 + ((part ^ (row & 15)) * 8)] =
        *(const half8*)&ymix[(rowbase + row) * 128 + part * 8];
    *(half8*)&sW[row * 128 + ((part ^ (row & 15)) * 8)] =
        *(const half8*)&wfa[row * 128 + part * 8];
  }
  __syncthreads();
  // GEMM1: C[co][px] = sum_ci wa[co][ci] * ymix[px][ci]
  f32x4 acc[4][4];
  zero_acc(acc);
#pragma unroll
  for (int ks = 0; ks < 4; ++ks) gemm_step<16>(sW, sAct, m0, n0, ks * 4, lane, acc);
  __syncthreads();  // GEMM1 LDS reads done before overwriting

  // epilogue1: mid = gelu(silu(t*ga+ba)) -> sAct (as [px][ci]); stage wb -> sW
#pragma unroll
  for (int mt = 0; mt < 4; ++mt) {
#pragma unroll
    for (int r = 0; r < 4; ++r) {
      int co = m0 + mt * 16 + (lane >> 4) * 4 + r;
      float gg = ga[co], sh = ba[co];
#pragma unroll
      for (int nt = 0; nt < 4; ++nt) {
        int px = n0 + nt * 16 + (lane & 15);
        float y = acc[mt][nt][r] * gg + sh;
        float sv = silu_f(y);
        float gl = 0.5f * sv * (1.f + erff(sv * 0.70710678118f));
        sAct[px * 128 + (((co >> 3) ^ (px & 15)) * 8) + (co & 7)] = (_Float16)gl;
      }
    }
  }
  for (int it = 0; it < 8; ++it) {
    int lid = tid + it * 256;
    int co = lid >> 4, part = lid & 15;
    *(half8*)&sW[co * 128 + ((part ^ (co & 15)) * 8)] =
        *(const half8*)&wfb[co * 128 + part * 8];
  }
  __syncthreads();
  // GEMM2: C[co][px] = sum_ci wb[co][ci] * mid[px][ci]
  f32x4 acc2[4][4];
  zero_acc(acc2);
#pragma unroll
  for (int ks = 0; ks < 4; ++ks) gemm_step<16>(sW, sAct, m0, n0, ks * 4, lane, acc2);

#pragma unroll
  for (int mt = 0; mt < 4; ++mt) {
#pragma unroll
    for (int r = 0; r < 4; ++r) {
      int co = m0 + mt * 16 + (lane >> 4) * 4 + r;
      float gg = gb[co], sh = bbv[co];
      size_t base = (size_t)(b * 128 + co) * 65536 + i * 256 + jh * 128;
#pragma unroll
      for (int nt = 0; nt < 4; ++nt) {
        int px = n0 + nt * 16 + (lane & 15);
        float y = acc2[mt][nt][r] * gg + sh;
        out[base + px] = silu_f(y) * x[base + px];  // * residual, NCHW fp32
      }
    }
  }
}

// ---------------------------------------------------------------------------
extern "C" void kernel_launch(void* const* d_in, const int* in_sizes, int n_in,
                              void* d_out, int out_size, void* d_ws, size_t ws_size,
                              hipStream_t stream) {
  (void)in_sizes; (void)n_in; (void)out_size; (void)ws_size;
  const float* x  = (const float*)d_in[0];
  const float* w1 = (const float*)d_in[1];
  const float* g1 = (const float*)d_in[2];
  const float* b1 = (const float*)d_in[3];
  const float* w2 = (const float*)d_in[4];
  const float* g2 = (const float*)d_in[5];
  const float* b2 = (const float*)d_in[6];
  const float* w3 = (const float*)d_in[7];
  const float* g3 = (const float*)d_in[8];
  const float* b3 = (const float*)d_in[9];
  const float* wm = (const float*)d_in[10];
  const float* gm = (const float*)d_in[11];
  const float* bm = (const float*)d_in[12];
  const float* wa = (const float*)d_in[13];
  const float* ga = (const float*)d_in[14];
  const float* ba = (const float*)d_in[15];
  const float* wb = (const float*)d_in[16];
  const float* gb = (const float*)d_in[17];
  const float* bb = (const float*)d_in[18];

  char* ws = (char*)d_ws;
  float*    bins = (float*)(ws + OFF_BINS);
  float*    inv  = (float*)(ws + OFF_INV);
  _Float16* wf16 = (_Float16*)(ws + OFF_WF);
  _Float16* amat = (_Float16*)(ws + OFF_AMAT);
  _Float16* cat  = (_Float16*)(ws + OFF_CAT);
  _Float16* ymix = (_Float16*)(ws + OFF_YMIX);
  float*    out  = (float*)d_out;

  hipMemsetAsync(bins, 0, 64, stream);
  k_prep<<<512, 256, 0, stream>>>(w1, w2, w3, wa, wb, wm, wf16, amat);
  k_transpose<<<4096, 256, 0, stream>>>(x, cat, bins);
  k_invm<<<1, 64, 0, stream>>>(bins, inv);
  k1_sconv<<<2048, 256, 0, stream>>>(cat, wf16, g1, b1, g2, b2, g3, b3, inv);
  k2_mix<<<2048, 256, 0, stream>>>(cat, amat, gm, bm, ymix);
  k3_tail<<<2048, 256, 0, stream>>>(ymix, wf16 + 3 * 16384, wf16 + 4 * 16384,
                                    ga, ba, gb, bb, x, out);
}